// Round 6
// baseline (36.741 us; speedup 1.0000x reference)
//
#include <hip/hip_runtime.h>

#define NR_ACTIONS 64
#define VEC 512
#define NTILE 16        // output columns per block (one 16-col MFMA tile)
#define MAXB 2048       // fast-scan path size

typedef short bf16x8  __attribute__((ext_vector_type(8)));
typedef float f32x4   __attribute__((ext_vector_type(4)));
typedef uint  uint32x2 __attribute__((ext_vector_type(2)));

__device__ __forceinline__ ushort f2bf(float f) {
    union { float f; uint32_t u; } x; x.f = f;
    uint32_t r = x.u + 0x7FFFu + ((x.u >> 16) & 1u);   // RNE
    return (ushort)(r >> 16);
}
__device__ __forceinline__ uint32_t pack2(float a, float b) {
    return (uint32_t)f2bf(a) | ((uint32_t)f2bf(b) << 16);
}
__device__ __forceinline__ uint32_t lds_addr(const void* p) {
    return (uint32_t)(uintptr_t)(__attribute__((address_space(3))) const void*)p;
}

// ---- prep: v fp32 -> bf16 once ----
__global__ __launch_bounds__(256) void cvt_v_kernel(const float* __restrict__ v,
                                                    ushort* __restrict__ vbf, int n8) {
    const int i = blockIdx.x * 256 + threadIdx.x;
    if (i < n8) {
        const float4 x = ((const float4*)v)[2 * i];
        const float4 y = ((const float4*)v)[2 * i + 1];
        uint4 o;
        o.x = pack2(x.x, x.y); o.y = pack2(x.z, x.w);
        o.z = pack2(y.x, y.y); o.w = pack2(y.z, y.w);
        ((uint4*)vbf)[i] = o;
    }
}

// ---- main: one block = one (action, 16-col) tile ----
// global_load_lds fp32 [k][16] -> in-place cvt to bf16 [k][16] (once/block)
// -> compute with ds_read_b64_tr_b16 B-fragments (2/k-step, no per-ks cvt).
template <bool BF>
__global__ __launch_bounds__(256) void grouped(
    const float* __restrict__ v, const ushort* __restrict__ vbf,
    const int* __restrict__ action, const float* __restrict__ W,
    float* __restrict__ out, int batch)
{
    __shared__ float  sWf[NTILE * VEC];   // 32 KB fp32 [k][16]; low 16 KB reused as bf16
    __shared__ ushort slist[64];
    __shared__ int    smc;

    const int h    = blockIdx.x;
    const int l    = (h & 7) * ((int)gridDim.x >> 3) + (h >> 3);  // XCD-bijective (nwg%8==0)
    const int a    = l >> 5;
    const int j0   = (l & 31) * NTILE;
    const int tid  = threadIdx.x;
    const int lane = tid & 63;
    const int wv   = tid >> 6;

    const float* Wa = W + (size_t)a * VEC * VEC + j0;

    // wave0: issue the 32 independent action loads FIRST (vmcnt in-order per wave)
    const bool fast = (batch == MAXB);
    int av[32];
    if (wv == 0 && fast) {
#pragma unroll
        for (int c = 0; c < 32; ++c) av[c] = action[c * 64 + lane];
    }

    // fire-and-forget W tile -> LDS fp32 [k][16]
    {
        const int col4 = (lane & 3) * 4;
        const int krow = lane >> 2;
#pragma unroll
        for (int c = 0; c < 8; ++c) {
            const int kr = (wv * 8 + c) * 16 + krow;
            const float* gp = Wa + (size_t)kr * VEC + col4;
            __builtin_amdgcn_global_load_lds(
                (const __attribute__((address_space(1))) void*)gp,
                (__attribute__((address_space(3))) void*)&sWf[(wv * 8 + c) * 256],
                16, 0, 0);
        }
    }

    // wave0: ordered window-0 list (register-only ballot chain on fast path)
    if (wv == 0) {
        int base = 0;
        if (fast) {
#pragma unroll
            for (int c = 0; c < 32; ++c) {
                const bool hit = (av[c] == a);
                const unsigned long long mk = __ballot(hit);
                const int pos = base + __popcll(mk & ((1ull << lane) - 1ull));
                if (hit && pos < 64) slist[pos] = (ushort)(c * 64 + lane);
                base += __popcll(mk);
            }
        } else {
            for (int it = 0; it < batch; it += 64) {
                const int idx = it + lane;
                const bool hit = (idx < batch) && (action[idx] == a);
                const unsigned long long mk = __ballot(hit);
                const int pos = base + __popcll(mk & ((1ull << lane) - 1ull));
                if (hit && pos < 64) slist[pos] = (ushort)idx;
                base += __popcll(mk);
            }
        }
        if (lane == 0) smc = base;
    }

    __syncthreads();   // W tile landed + slist/smc published

    // ---- pass A: fp32 -> bf16 in place, once per block (conflict-free) ----
    float4 wf[8];
#pragma unroll
    for (int i = 0; i < 8; ++i)
        wf[i] = *(const float4*)&sWf[(tid + 256 * i) * 4];
    __syncthreads();   // all fp32 reads done before overwriting
    ushort* sWb = (ushort*)sWf;   // bf16 [k][16], elem idx = k*16+col (identity map)
#pragma unroll
    for (int i = 0; i < 8; ++i) {
        uint2 p;
        p.x = pack2(wf[i].x, wf[i].y);
        p.y = pack2(wf[i].z, wf[i].w);
        *(uint2*)&sWb[(tid + 256 * i) * 4] = p;
    }
    __syncthreads();

    const int m      = smc;
    const int colg   = j0 + (lane & 15);
    const int g      = lane >> 4;
    const int wstart = wv * 16;
    const uint32_t trbase = lds_addr(sWb) + (uint32_t)lane * 8u;

    for (int wlo = 0;;) {
        const int mw = min(64, m - wlo);
        if (mw > 0 && wstart < mw) {
            const int rl   = wstart + (lane & 15);
            const int ridx = slist[rl < mw ? rl : wstart];   // clamp: discarded at store
            f32x4 acc = {0.f, 0.f, 0.f, 0.f};
            // kperm(g,e): e<4 -> ks*32 + g*4 + e ; e>=4 -> ks*32 + 16 + g*4 + (e-4).
            // tr_b16 delivers B in exactly this permutation; A mirrors it below.
#pragma unroll
            for (int ks = 0; ks < 16; ++ks) {
                uint32x2 t0, t1;
                const uint32_t ad = trbase + (uint32_t)(ks * 1024);
                asm volatile("ds_read_b64_tr_b16 %0, %1 offset:0"   : "=v"(t0) : "v"(ad));
                asm volatile("ds_read_b64_tr_b16 %0, %1 offset:512" : "=v"(t1) : "v"(ad));
                union { uint32_t u[4]; bf16x8 vv; } au, bu;
                if (BF) {
                    const ushort* ap = vbf + (size_t)ridx * VEC + ks * 32 + g * 4;
                    const uint2 alo = *(const uint2*)(ap);
                    const uint2 ahi = *(const uint2*)(ap + 16);
                    au.u[0] = alo.x; au.u[1] = alo.y; au.u[2] = ahi.x; au.u[3] = ahi.y;
                } else {
                    const float* ap = v + (size_t)ridx * VEC + ks * 32 + g * 4;
                    const float4 f0 = *(const float4*)(ap);
                    const float4 f1 = *(const float4*)(ap + 16);
                    au.u[0] = pack2(f0.x, f0.y); au.u[1] = pack2(f0.z, f0.w);
                    au.u[2] = pack2(f1.x, f1.y); au.u[3] = pack2(f1.z, f1.w);
                }
                asm volatile("s_waitcnt lgkmcnt(0)" ::: "memory");  // tr reads landed
                __builtin_amdgcn_sched_barrier(0);                  // rule #18 fence
                bu.u[0] = t0[0]; bu.u[1] = t0[1]; bu.u[2] = t1[0]; bu.u[3] = t1[1];
                acc = __builtin_amdgcn_mfma_f32_16x16x32_bf16(au.vv, bu.vv, acc, 0, 0, 0);
            }
            // D layout: col=lane&15, row=(lane>>4)*4+q (m89-verified)
#pragma unroll
            for (int q = 0; q < 4; ++q) {
                const int row = wstart + g * 4 + q;
                if (row < mw)
                    out[(size_t)slist[row] * VEC + colg] = acc[q];
            }
        }
        wlo += 64;
        if (wlo >= m) break;   // uniform; common case: no extra barriers
        // rare path (group > 64 rows): rebuild ordered window list
        __syncthreads();
        if (wv == 0) {
            int base = 0;
            for (int it = 0; it < batch; it += 64) {
                const int idx = it + lane;
                const bool hit = (idx < batch) && (action[idx] == a);
                const unsigned long long mk = __ballot(hit);
                const int rp = base + __popcll(mk & ((1ull << lane) - 1ull)) - wlo;
                if (hit && rp >= 0 && rp < 64) slist[rp] = (ushort)idx;
                base += __popcll(mk);
            }
        }
        __syncthreads();
    }
}

extern "C" void kernel_launch(void* const* d_in, const int* in_sizes, int n_in,
                              void* d_out, int out_size, void* d_ws, size_t ws_size,
                              hipStream_t stream) {
    const float* v      = (const float*)d_in[0];
    const int*   action = (const int*)d_in[1];
    const float* W      = (const float*)d_in[2];
    float* out = (float*)d_out;
    const int batch = in_sizes[1];
    if (batch <= 0) return;

    const int nblocks = (VEC / NTILE) * NR_ACTIONS;   // 2048 (%8==0 for swizzle)
    const size_t need = (size_t)batch * VEC * sizeof(ushort);

    if (ws_size >= need && ((size_t)batch * VEC) % 8 == 0) {
        ushort* vbf = (ushort*)d_ws;
        const int n8 = (int)((size_t)batch * VEC / 8);
        cvt_v_kernel<<<(n8 + 255) / 256, 256, 0, stream>>>(v, vbf, n8);
        grouped<true><<<nblocks, 256, 0, stream>>>(v, vbf, action, W, out, batch);
    } else {
        grouped<false><<<nblocks, 256, 0, stream>>>(v, (const ushort*)nullptr,
                                                    action, W, out, batch);
    }
}

// Round 7
// 30.077 us; speedup vs baseline: 1.2216x; 1.2216x over previous
//
#include <hip/hip_runtime.h>

#define NR_ACTIONS 64
#define VEC 512
#define NTILE 16        // output columns per block (one 16-col MFMA tile)
#define MAXB 2048       // fast-scan path size

typedef short bf16x8 __attribute__((ext_vector_type(8)));
typedef float f32x4  __attribute__((ext_vector_type(4)));

__device__ __forceinline__ ushort f2bf(float f) {
    union { float f; uint32_t u; } x; x.f = f;
    uint32_t r = x.u + 0x7FFFu + ((x.u >> 16) & 1u);   // RNE
    return (ushort)(r >> 16);
}
__device__ __forceinline__ uint32_t pack2(float a, float b) {
    return (uint32_t)f2bf(a) | ((uint32_t)f2bf(b) << 16);
}

// ---- prep: v fp32 -> bf16 once ----
__global__ __launch_bounds__(256) void cvt_v_kernel(const float* __restrict__ v,
                                                    ushort* __restrict__ vbf, int n8) {
    const int i = blockIdx.x * 256 + threadIdx.x;
    if (i < n8) {
        const float4 x = ((const float4*)v)[2 * i];
        const float4 y = ((const float4*)v)[2 * i + 1];
        uint4 o;
        o.x = pack2(x.x, x.y); o.y = pack2(x.z, x.w);
        o.z = pack2(y.x, y.y); o.w = pack2(y.z, y.w);
        ((uint4*)vbf)[i] = o;
    }
}

// ---- main: one block = one (action, 16-col) tile ----
// Phase 1: global_load_lds fp32 [k][16] (linear, coalesced) + wave0 ballot scan.
// Phase 2: once-per-block transpose+cvt: fp32 [k][16] -> bf16 [c][k] XOR-swizzled
//          (in place, regs between two barriers).
// Phase 3: MFMA loop — 1 conflict-free ds_read_b128 per k-step, A prefetched,
//          no fences (compiler-scheduled lgkmcnt).
template <bool BF>
__global__ __launch_bounds__(256) void grouped(
    const float* __restrict__ v, const ushort* __restrict__ vbf,
    const int* __restrict__ action, const float* __restrict__ W,
    float* __restrict__ out, int batch)
{
    __shared__ float  sWf[NTILE * VEC];   // 32 KB fp32 [k][16]; low 16 KB reused as bf16 [c][k]
    __shared__ ushort slist[64];
    __shared__ int    smc;

    const int h    = blockIdx.x;
    const int l    = (h & 7) * ((int)gridDim.x >> 3) + (h >> 3);  // XCD-bijective (nwg%8==0)
    const int a    = l >> 5;
    const int j0   = (l & 31) * NTILE;
    const int tid  = threadIdx.x;
    const int lane = tid & 63;
    const int wv   = tid >> 6;

    const float* Wa = W + (size_t)a * VEC * VEC + j0;

    // wave0: issue the 32 independent action loads FIRST (vmcnt in-order per wave)
    const bool fast = (batch == MAXB);
    int av[32];
    if (wv == 0 && fast) {
#pragma unroll
        for (int c = 0; c < 32; ++c) av[c] = action[c * 64 + lane];
    }

    // fire-and-forget W tile -> LDS fp32 [k][16] (linear dest, proven R5 pattern)
    {
        const int col4 = (lane & 3) * 4;
        const int krow = lane >> 2;
#pragma unroll
        for (int c = 0; c < 8; ++c) {
            const int kr = (wv * 8 + c) * 16 + krow;
            const float* gp = Wa + (size_t)kr * VEC + col4;
            __builtin_amdgcn_global_load_lds(
                (const __attribute__((address_space(1))) void*)gp,
                (__attribute__((address_space(3))) void*)&sWf[(wv * 8 + c) * 256],
                16, 0, 0);
        }
    }

    // wave0: ordered window-0 list (register-only ballot chain on fast path)
    if (wv == 0) {
        int base = 0;
        if (fast) {
#pragma unroll
            for (int c = 0; c < 32; ++c) {
                const bool hit = (av[c] == a);
                const unsigned long long mk = __ballot(hit);
                const int pos = base + __popcll(mk & ((1ull << lane) - 1ull));
                if (hit && pos < 64) slist[pos] = (ushort)(c * 64 + lane);
                base += __popcll(mk);
            }
        } else {
            for (int it = 0; it < batch; it += 64) {
                const int idx = it + lane;
                const bool hit = (idx < batch) && (action[idx] == a);
                const unsigned long long mk = __ballot(hit);
                const int pos = base + __popcll(mk & ((1ull << lane) - 1ull));
                if (hit && pos < 64) slist[pos] = (ushort)idx;
                base += __popcll(mk);
            }
        }
        if (lane == 0) smc = base;
    }

    __syncthreads();   // B1: W tile landed + slist/smc published
    const int m = smc;
    if (m == 0) return;

    // ---- Phase 2: transpose + cvt, once per block ----
    // thread (c=lane&15, g=lane>>4, wv) owns dest ks = [wv*128 + g*32, +32) for col c
    const int tc  = lane & 15;
    const int tg  = lane >> 4;
    const int kb0 = wv * 128 + tg * 32;
    float tv[32];
#pragma unroll
    for (int kk = 0; kk < 32; ++kk)
        tv[kk] = sWf[(kb0 + kk) * 16 + tc];     // 4-way conflict, once per block
    __syncthreads();   // B2: all fp32 reads done before overwrite
    char* sWbase = (char*)sWf;                   // bf16 [c][k], byte = c*1024 + k*2, ^ (c&7)<<4
#pragma unroll
    for (int e8 = 0; e8 < 4; ++e8) {
        uint4 p;
        p.x = pack2(tv[e8 * 8 + 0], tv[e8 * 8 + 1]);
        p.y = pack2(tv[e8 * 8 + 2], tv[e8 * 8 + 3]);
        p.z = pack2(tv[e8 * 8 + 4], tv[e8 * 8 + 5]);
        p.w = pack2(tv[e8 * 8 + 6], tv[e8 * 8 + 7]);
        const uint32_t off = (uint32_t)(tc * 1024 + (kb0 + e8 * 8) * 2) ^ ((uint32_t)(tc & 7) << 4);
        *(uint4*)(sWbase + off) = p;             // 2-way per quarter-wave = free
    }
    __syncthreads();   // B3: bf16 tile ready

    // ---- Phase 3: MFMA ----
    const int colg   = j0 + (lane & 15);
    const int g      = lane >> 4;
    const int wstart = wv * 16;

    for (int wlo = 0;;) {
        const int mw = min(64, m - wlo);
        if (mw > 0 && wstart < mw) {
            const int rl   = wstart + (lane & 15);
            const int ridx = slist[rl < mw ? rl : wstart];   // clamp: discarded at store

            // prefetch all 16 A-fragments (independent, all in flight)
            bf16x8 afr[16];
            if (BF) {
                const ushort* ap = vbf + (size_t)ridx * VEC + g * 8;
#pragma unroll
                for (int ks = 0; ks < 16; ++ks)
                    afr[ks] = *(const bf16x8*)(ap + ks * 32);
            } else {
                const float* ap = v + (size_t)ridx * VEC + g * 8;
#pragma unroll
                for (int ks = 0; ks < 16; ++ks) {
                    const float4 f0 = *(const float4*)(ap + ks * 32);
                    const float4 f1 = *(const float4*)(ap + ks * 32 + 4);
                    union { uint32_t u[4]; bf16x8 s; } au;
                    au.u[0] = pack2(f0.x, f0.y); au.u[1] = pack2(f0.z, f0.w);
                    au.u[2] = pack2(f1.x, f1.y); au.u[3] = pack2(f1.z, f1.w);
                    afr[ks] = au.s;
                }
            }

            f32x4 acc = {0.f, 0.f, 0.f, 0.f};
            // k-map for A and B identical: k = ks*32 + g*8 + e  -> contraction exact
#pragma unroll
            for (int ks = 0; ks < 16; ++ks) {
                const uint32_t boff =
                    ((uint32_t)((lane & 15) * 1024 + (ks * 32 + g * 8) * 2)) ^
                    ((uint32_t)((lane & 15) & 7) << 4);
                const bf16x8 bfrag = *(const bf16x8*)(sWbase + boff);
                acc = __builtin_amdgcn_mfma_f32_16x16x32_bf16(afr[ks], bfrag, acc, 0, 0, 0);
            }

            // D layout: col=lane&15, row=(lane>>4)*4+q (m89-verified)
#pragma unroll
            for (int q = 0; q < 4; ++q) {
                const int row = wstart + g * 4 + q;
                if (row < mw)
                    out[(size_t)slist[row] * VEC + colg] = acc[q];
            }
        }
        wlo += 64;
        if (wlo >= m) break;   // uniform; common case: no extra barriers
        // rare path (group > 64 rows): rebuild ordered window list
        __syncthreads();
        if (wv == 0) {
            int base = 0;
            for (int it = 0; it < batch; it += 64) {
                const int idx = it + lane;
                const bool hit = (idx < batch) && (action[idx] == a);
                const unsigned long long mk = __ballot(hit);
                const int rp = base + __popcll(mk & ((1ull << lane) - 1ull)) - wlo;
                if (hit && rp >= 0 && rp < 64) slist[rp] = (ushort)idx;
                base += __popcll(mk);
            }
        }
        __syncthreads();
    }
}

extern "C" void kernel_launch(void* const* d_in, const int* in_sizes, int n_in,
                              void* d_out, int out_size, void* d_ws, size_t ws_size,
                              hipStream_t stream) {
    const float* v      = (const float*)d_in[0];
    const int*   action = (const int*)d_in[1];
    const float* W      = (const float*)d_in[2];
    float* out = (float*)d_out;
    const int batch = in_sizes[1];
    if (batch <= 0) return;

    const int nblocks = (VEC / NTILE) * NR_ACTIONS;   // 2048 (%8==0 for swizzle)
    const size_t need = (size_t)batch * VEC * sizeof(ushort);

    if (ws_size >= need && ((size_t)batch * VEC) % 8 == 0) {
        ushort* vbf = (ushort*)d_ws;
        const int n8 = (int)((size_t)batch * VEC / 8);
        cvt_v_kernel<<<(n8 + 255) / 256, 256, 0, stream>>>(v, vbf, n8);
        grouped<true><<<nblocks, 256, 0, stream>>>(v, vbf, action, W, out, batch);
    } else {
        grouped<false><<<nblocks, 256, 0, stream>>>(v, (const ushort*)nullptr,
                                                    action, W, out, batch);
    }
}